// Round 6
// baseline (10436.451 us; speedup 1.0000x reference)
//
#include <hip/hip_runtime.h>

#define USER_NUM 200000
#define ITEM_NUM 100000
#define N_NODES  (USER_NUM + ITEM_NUM)
#define EMB      64
#define NNZ      9600000

#define RPB      128                                // rows per bucket
#define NBUCK    ((N_NODES + RPB - 1) / RPB)        // 2344
#define CHUNK_I4 4096                               // int4s per block = 16384 edges
#define NEBLK    ((NNZ / 4 + CHUNK_I4 - 1) / CHUNK_I4)  // 586

// ===========================================================================
// init: X = concat(user_emb, item_emb); out = X
// ===========================================================================
__global__ __launch_bounds__(256) void init_nodes_kernel(
    const float* __restrict__ user_emb,
    const float* __restrict__ item_emb,
    float* __restrict__ X,
    float* __restrict__ out) {
  const long total4 = (long)N_NODES * EMB / 4;
  long g = (long)blockIdx.x * blockDim.x + threadIdx.x;
  if (g >= total4) return;
  const long user4 = (long)USER_NUM * EMB / 4;
  float4 v;
  if (g < user4) v = ((const float4*)user_emb)[g];
  else           v = ((const float4*)item_emb)[g - user4];
  ((float4*)X)[g]   = v;
  ((float4*)out)[g] = v;
}

__global__ __launch_bounds__(256) void zero_buckets_kernel(int* __restrict__ gcnt) {
  int i = blockIdx.x * 256 + threadIdx.x;
  if (i < NBUCK) gcnt[i] = 0;
}

// ===========================================================================
// bucket histogram: LDS hist per block, merged with one atomic per bucket
// ===========================================================================
__global__ __launch_bounds__(256) void hist_bucket_kernel(
    const int* __restrict__ rows, int* __restrict__ gcnt) {
  __shared__ int lcnt[NBUCK];
  for (int i = threadIdx.x; i < NBUCK; i += 256) lcnt[i] = 0;
  __syncthreads();
  const int n4 = NNZ / 4;
  const int base = blockIdx.x * CHUNK_I4;
  for (int i = threadIdx.x; i < CHUNK_I4; i += 256) {
    int idx = base + i;
    if (idx < n4) {
      int4 r = ((const int4*)rows)[idx];
      atomicAdd(&lcnt[r.x >> 7], 1);
      atomicAdd(&lcnt[r.y >> 7], 1);
      atomicAdd(&lcnt[r.z >> 7], 1);
      atomicAdd(&lcnt[r.w >> 7], 1);
    }
  }
  __syncthreads();
  for (int b = threadIdx.x; b < NBUCK; b += 256) {
    int c = lcnt[b];
    if (c) atomicAdd(&gcnt[b], c);
  }
}

// ===========================================================================
// exclusive scan of 2344 bucket counts (single block, chunked); gcur = gbase
// ===========================================================================
__global__ __launch_bounds__(256) void scan_buckets_kernel(
    const int* __restrict__ gcnt, int* __restrict__ gbase, int* __restrict__ gcur) {
  __shared__ int sh[256];
  __shared__ int carry_sh;
  int tid = threadIdx.x;
  if (tid == 0) carry_sh = 0;
  __syncthreads();
  for (int base = 0; base < NBUCK; base += 256) {
    int idx = base + tid;
    int v = (idx < NBUCK) ? gcnt[idx] : 0;
    sh[tid] = v; __syncthreads();
#pragma unroll
    for (int ofs = 1; ofs < 256; ofs <<= 1) {
      int t = (tid >= ofs) ? sh[tid - ofs] : 0;
      __syncthreads();
      sh[tid] += t;
      __syncthreads();
    }
    int excl = carry_sh + sh[tid] - v;
    if (idx < NBUCK) { gbase[idx] = excl; gcur[idx] = excl; }
    int tot = sh[255];
    __syncthreads();
    if (tid == 0) carry_sh += tot;
    __syncthreads();
  }
}

// ===========================================================================
// bucket scatter: per-chunk LDS hist -> per-bucket reservation -> packed write
// packed edge: meta = (rowlocal<<19) | col  (col < 2^19, rowlocal < 128)
// ===========================================================================
__global__ __launch_bounds__(256) void scatter_bucket_kernel(
    const int* __restrict__ rows, const int* __restrict__ cols,
    const float* __restrict__ vals, int* __restrict__ gcur,
    int2* __restrict__ CV) {
  __shared__ int lcnt[NBUCK];
  __shared__ int lofs[NBUCK];
  for (int i = threadIdx.x; i < NBUCK; i += 256) lcnt[i] = 0;
  __syncthreads();
  const int n4 = NNZ / 4;
  const int base = blockIdx.x * CHUNK_I4;
  // pass A: local histogram
  for (int i = threadIdx.x; i < CHUNK_I4; i += 256) {
    int idx = base + i;
    if (idx < n4) {
      int4 r = ((const int4*)rows)[idx];
      atomicAdd(&lcnt[r.x >> 7], 1);
      atomicAdd(&lcnt[r.y >> 7], 1);
      atomicAdd(&lcnt[r.z >> 7], 1);
      atomicAdd(&lcnt[r.w >> 7], 1);
    }
  }
  __syncthreads();
  // reserve global space, one atomic per (chunk, bucket)
  for (int b = threadIdx.x; b < NBUCK; b += 256) {
    int c = lcnt[b];
    lofs[b] = c ? atomicAdd(&gcur[b], c) : 0;
    lcnt[b] = 0;                       // reuse as within-chunk cursor
  }
  __syncthreads();
  // pass B: scatter packed edges
  for (int i = threadIdx.x; i < CHUNK_I4; i += 256) {
    int idx = base + i;
    if (idx < n4) {
      int4   r = ((const int4*)rows)[idx];
      int4   c = ((const int4*)cols)[idx];
      float4 v = ((const float4*)vals)[idx];
      int b0, p;
      b0 = r.x >> 7; p = atomicAdd(&lcnt[b0], 1);
      CV[lofs[b0] + p] = make_int2(((r.x & 127) << 19) | c.x, __float_as_int(v.x));
      b0 = r.y >> 7; p = atomicAdd(&lcnt[b0], 1);
      CV[lofs[b0] + p] = make_int2(((r.y & 127) << 19) | c.y, __float_as_int(v.y));
      b0 = r.z >> 7; p = atomicAdd(&lcnt[b0], 1);
      CV[lofs[b0] + p] = make_int2(((r.z & 127) << 19) | c.z, __float_as_int(v.z));
      b0 = r.w >> 7; p = atomicAdd(&lcnt[b0], 1);
      CV[lofs[b0] + p] = make_int2(((r.w & 127) << 19) | c.w, __float_as_int(v.w));
    }
  }
}

// ===========================================================================
// bucket SpMM: one workgroup per bucket, LDS accumulator, no global atomics.
// FINAL==0: y = A*x ; out += y       FINAL==1: out = (out + A*x) * 0.25
// ===========================================================================
template <int FINAL>
__global__ __launch_bounds__(256) void spmm_bucket_kernel(
    const int*  __restrict__ gbase, const int* __restrict__ gcnt,
    const int2* __restrict__ CV, const float* __restrict__ x,
    float* __restrict__ y, float* __restrict__ out) {
  __shared__ float acc[RPB * EMB];                 // 32 KB
  for (int i = threadIdx.x; i < RPB * EMB / 4; i += 256)
    ((float4*)acc)[i] = make_float4(0.f, 0.f, 0.f, 0.f);
  __syncthreads();

  const int b = blockIdx.x;
  const int s = gbase[b];
  const int e = s + gcnt[b];
  const int lane = threadIdx.x & 63;
  const int w = threadIdx.x >> 6;

  for (int batch = s + (w << 6); batch < e; batch += 256) {
    const int cnt = min(64, e - batch);
    int2 ed = (batch + lane < e) ? CV[batch + lane] : make_int2(0, 0);
    if (cnt == 64) {
#pragma unroll 4
      for (int j = 0; j < 64; ++j) {
        int   m  = __builtin_amdgcn_readlane(ed.x, j);
        float vv = __int_as_float(__builtin_amdgcn_readlane(ed.y, j));
        int col = m & 0x7FFFF;
        int rl  = m >> 19;
        float xv = x[col * EMB + lane];            // wave-uniform col: 256B coalesced
        atomicAdd(&acc[rl * EMB + lane], vv * xv); // ds_add_f32, conflict-free
      }
    } else {
      for (int j = 0; j < cnt; ++j) {
        int   m  = __builtin_amdgcn_readlane(ed.x, j);
        float vv = __int_as_float(__builtin_amdgcn_readlane(ed.y, j));
        int col = m & 0x7FFFF;
        int rl  = m >> 19;
        float xv = x[col * EMB + lane];
        atomicAdd(&acc[rl * EMB + lane], vv * xv);
      }
    }
  }
  __syncthreads();

  const int rbase = b * RPB;
  for (int i = threadIdx.x; i < RPB * EMB; i += 256) {
    int r = rbase + (i >> 6);
    if (r < N_NODES) {
      int o = r * EMB + (i & 63);
      float a = acc[i];
      if (FINAL) out[o] = (out[o] + a) * 0.25f;
      else       { y[o] = a; out[o] += a; }
    }
  }
}

// ===========================================================================
// Fallback (round-1 atomic path) if ws_size is too small
// ===========================================================================
__global__ __launch_bounds__(256) void init_kernel_fb(
    const float* __restrict__ user_emb, const float* __restrict__ item_emb,
    float* __restrict__ X, float* __restrict__ Y, float* __restrict__ out) {
  const long total4 = (long)N_NODES * EMB / 4;
  long g = (long)blockIdx.x * blockDim.x + threadIdx.x;
  if (g >= total4) return;
  const long user4 = (long)USER_NUM * EMB / 4;
  float4 v;
  if (g < user4) v = ((const float4*)user_emb)[g];
  else           v = ((const float4*)item_emb)[g - user4];
  ((float4*)X)[g]   = v;
  ((float4*)out)[g] = v;
  ((float4*)Y)[g]   = make_float4(0.f, 0.f, 0.f, 0.f);
}

__global__ __launch_bounds__(256) void spmm_atomic_kernel_fb(
    const float* __restrict__ vals, const int* __restrict__ rows,
    const int* __restrict__ cols, const float* __restrict__ x,
    float* __restrict__ y) {
  const int lane = threadIdx.x & 63;
  int wave = blockIdx.x * (blockDim.x >> 6) + (threadIdx.x >> 6);
  wave = __builtin_amdgcn_readfirstlane(wave);
  const int nwaves = gridDim.x * (blockDim.x >> 6);
  constexpr int U = 4;
  for (long base = (long)wave * U; base < NNZ; base += (long)nwaves * U) {
    int r[U], c[U]; float v[U];
#pragma unroll
    for (int u = 0; u < U; ++u) { r[u] = rows[base+u]; c[u] = cols[base+u]; v[u] = vals[base+u]; }
#pragma unroll
    for (int u = 0; u < U; ++u) {
      float xv = x[(long)c[u] * EMB + lane];
      unsafeAtomicAdd(&y[(long)r[u] * EMB + lane], v[u] * xv);
    }
  }
}

__global__ __launch_bounds__(256) void add_zero_kernel_fb(
    float* __restrict__ out, const float* __restrict__ S, float* __restrict__ Z) {
  const long total4 = (long)N_NODES * EMB / 4;
  long g = (long)blockIdx.x * blockDim.x + threadIdx.x;
  if (g >= total4) return;
  float4 a = ((float4*)out)[g];
  float4 s = ((const float4*)S)[g];
  a.x += s.x; a.y += s.y; a.z += s.z; a.w += s.w;
  ((float4*)out)[g] = a;
  ((float4*)Z)[g]   = make_float4(0.f, 0.f, 0.f, 0.f);
}

__global__ __launch_bounds__(256) void final_kernel_fb(
    float* __restrict__ out, const float* __restrict__ S) {
  const long total4 = (long)N_NODES * EMB / 4;
  long g = (long)blockIdx.x * blockDim.x + threadIdx.x;
  if (g >= total4) return;
  float4 a = ((float4*)out)[g];
  float4 s = ((const float4*)S)[g];
  a.x = (a.x + s.x) * 0.25f; a.y = (a.y + s.y) * 0.25f;
  a.z = (a.z + s.z) * 0.25f; a.w = (a.w + s.w) * 0.25f;
  ((float4*)out)[g] = a;
}

// ===========================================================================
extern "C" void kernel_launch(void* const* d_in, const int* in_sizes, int n_in,
                              void* d_out, int out_size, void* d_ws, size_t ws_size,
                              hipStream_t stream) {
  const float* user_emb = (const float*)d_in[0];
  const float* item_emb = (const float*)d_in[1];
  const float* adj_vals = (const float*)d_in[2];
  const int*   adj_rows = (const int*)d_in[3];
  const int*   adj_cols = (const int*)d_in[4];
  float* out = (float*)d_out;

  const size_t nodeF = (size_t)N_NODES * EMB;
  const long total4 = (long)N_NODES * EMB / 4;
  const int ew_blocks = (int)((total4 + 255) / 256);

  // ws layout: X | Y | CV | gcnt | gbase | gcur
  float* X    = (float*)d_ws;
  float* Y    = X + nodeF;
  int2*  CV   = (int2*)(Y + nodeF);
  int*   gcnt = (int*)(CV + NNZ);
  int*   gbase = gcnt + NBUCK;
  int*   gcur  = gbase + NBUCK;
  const size_t need = 2 * nodeF * sizeof(float) + (size_t)NNZ * 8 + 3 * NBUCK * 4;

  if (ws_size >= need) {
    init_nodes_kernel<<<ew_blocks, 256, 0, stream>>>(user_emb, item_emb, X, out);
    zero_buckets_kernel<<<(NBUCK + 255) / 256, 256, 0, stream>>>(gcnt);
    hist_bucket_kernel<<<NEBLK, 256, 0, stream>>>(adj_rows, gcnt);
    scan_buckets_kernel<<<1, 256, 0, stream>>>(gcnt, gbase, gcur);
    scatter_bucket_kernel<<<NEBLK, 256, 0, stream>>>(adj_rows, adj_cols, adj_vals, gcur, CV);
    spmm_bucket_kernel<0><<<NBUCK, 256, 0, stream>>>(gbase, gcnt, CV, X, Y, out);
    spmm_bucket_kernel<0><<<NBUCK, 256, 0, stream>>>(gbase, gcnt, CV, Y, X, out);
    spmm_bucket_kernel<1><<<NBUCK, 256, 0, stream>>>(gbase, gcnt, CV, X, Y, out);
  } else {
    // fallback: atomic path
    float* Xf = (float*)d_ws;
    float* Yf = Xf + nodeF;
    const int spmm_blocks = 2048;
    init_kernel_fb<<<ew_blocks, 256, 0, stream>>>(user_emb, item_emb, Xf, Yf, out);
    spmm_atomic_kernel_fb<<<spmm_blocks, 256, 0, stream>>>(adj_vals, adj_rows, adj_cols, Xf, Yf);
    add_zero_kernel_fb<<<ew_blocks, 256, 0, stream>>>(out, Yf, Xf);
    spmm_atomic_kernel_fb<<<spmm_blocks, 256, 0, stream>>>(adj_vals, adj_rows, adj_cols, Yf, Xf);
    add_zero_kernel_fb<<<ew_blocks, 256, 0, stream>>>(out, Xf, Yf);
    spmm_atomic_kernel_fb<<<spmm_blocks, 256, 0, stream>>>(adj_vals, adj_rows, adj_cols, Xf, Yf);
    final_kernel_fb<<<ew_blocks, 256, 0, stream>>>(out, Yf);
  }
}

// Round 7
// 1548.695 us; speedup vs baseline: 6.7389x; 6.7389x over previous
//
#include <hip/hip_runtime.h>

#define USER_NUM 200000
#define ITEM_NUM 100000
#define N_NODES  (USER_NUM + ITEM_NUM)
#define EMB      64
#define NNZ      9600000

#define RPB      128                                // rows per bucket
#define NBUCK    ((N_NODES + RPB - 1) / RPB)        // 2344
#define CHUNK_I4 4096                               // int4s per chunk = 16384 edges
#define NEBLK    ((NNZ / 4 + CHUNK_I4 - 1) / CHUNK_I4)  // 586
#define CAP      6144                               // LDS sort capacity (bucket mean 4096, +32 sigma)

// ===========================================================================
// init: X = concat(user_emb, item_emb)   (out is fully written by spmm1)
// ===========================================================================
__global__ __launch_bounds__(256) void init_nodes_kernel(
    const float* __restrict__ user_emb,
    const float* __restrict__ item_emb,
    float* __restrict__ X) {
  const long total4 = (long)N_NODES * EMB / 4;
  long g = (long)blockIdx.x * blockDim.x + threadIdx.x;
  if (g >= total4) return;
  const long user4 = (long)USER_NUM * EMB / 4;
  float4 v;
  if (g < user4) v = ((const float4*)user_emb)[g];
  else           v = ((const float4*)item_emb)[g - user4];
  ((float4*)X)[g] = v;
}

__global__ __launch_bounds__(256) void zero_buckets_kernel(int* __restrict__ gcnt) {
  int i = blockIdx.x * 256 + threadIdx.x;
  if (i < NBUCK) gcnt[i] = 0;
}

// ===========================================================================
// bucket histogram: LDS (integer) hist per chunk, merged once per bucket
// ===========================================================================
__global__ __launch_bounds__(256) void hist_bucket_kernel(
    const int* __restrict__ rows, int* __restrict__ gcnt) {
  __shared__ int lcnt[NBUCK];
  for (int i = threadIdx.x; i < NBUCK; i += 256) lcnt[i] = 0;
  __syncthreads();
  const int n4 = NNZ / 4;
  const int base = blockIdx.x * CHUNK_I4;
  for (int i = threadIdx.x; i < CHUNK_I4; i += 256) {
    int idx = base + i;
    if (idx < n4) {
      int4 r = ((const int4*)rows)[idx];
      atomicAdd(&lcnt[r.x >> 7], 1);
      atomicAdd(&lcnt[r.y >> 7], 1);
      atomicAdd(&lcnt[r.z >> 7], 1);
      atomicAdd(&lcnt[r.w >> 7], 1);
    }
  }
  __syncthreads();
  for (int b = threadIdx.x; b < NBUCK; b += 256) {
    int c = lcnt[b];
    if (c) atomicAdd(&gcnt[b], c);
  }
}

// ===========================================================================
// exclusive scan of 2344 bucket counts (single block); gcur=gbase; off[N]=NNZ
// ===========================================================================
__global__ __launch_bounds__(256) void scan_buckets_kernel(
    const int* __restrict__ gcnt, int* __restrict__ gbase,
    int* __restrict__ gcur, int* __restrict__ off) {
  __shared__ int sh[256];
  __shared__ int carry_sh;
  int tid = threadIdx.x;
  if (tid == 0) { carry_sh = 0; off[N_NODES] = NNZ; }
  __syncthreads();
  for (int base = 0; base < NBUCK; base += 256) {
    int idx = base + tid;
    int v = (idx < NBUCK) ? gcnt[idx] : 0;
    sh[tid] = v; __syncthreads();
#pragma unroll
    for (int ofs = 1; ofs < 256; ofs <<= 1) {
      int t = (tid >= ofs) ? sh[tid - ofs] : 0;
      __syncthreads();
      sh[tid] += t;
      __syncthreads();
    }
    int excl = carry_sh + sh[tid] - v;
    if (idx < NBUCK) { gbase[idx] = excl; gcur[idx] = excl; }
    int tot = sh[255];
    __syncthreads();
    if (tid == 0) carry_sh += tot;
    __syncthreads();
  }
}

// ===========================================================================
// bucket scatter: per-chunk LDS hist -> per-(chunk,bucket) reservation ->
// packed contiguous runs.  meta = (rowlocal<<19) | col  (col < 2^19)
// ===========================================================================
__global__ __launch_bounds__(256) void scatter_bucket_kernel(
    const int* __restrict__ rows, const int* __restrict__ cols,
    const float* __restrict__ vals, int* __restrict__ gcur,
    int2* __restrict__ CV) {
  __shared__ int lcnt[NBUCK];
  __shared__ int lofs[NBUCK];
  for (int i = threadIdx.x; i < NBUCK; i += 256) lcnt[i] = 0;
  __syncthreads();
  const int n4 = NNZ / 4;
  const int base = blockIdx.x * CHUNK_I4;
  for (int i = threadIdx.x; i < CHUNK_I4; i += 256) {
    int idx = base + i;
    if (idx < n4) {
      int4 r = ((const int4*)rows)[idx];
      atomicAdd(&lcnt[r.x >> 7], 1);
      atomicAdd(&lcnt[r.y >> 7], 1);
      atomicAdd(&lcnt[r.z >> 7], 1);
      atomicAdd(&lcnt[r.w >> 7], 1);
    }
  }
  __syncthreads();
  for (int b = threadIdx.x; b < NBUCK; b += 256) {
    int c = lcnt[b];
    lofs[b] = c ? atomicAdd(&gcur[b], c) : 0;
    lcnt[b] = 0;                       // reuse as within-chunk cursor
  }
  __syncthreads();
  for (int i = threadIdx.x; i < CHUNK_I4; i += 256) {
    int idx = base + i;
    if (idx < n4) {
      int4   r = ((const int4*)rows)[idx];
      int4   c = ((const int4*)cols)[idx];
      float4 v = ((const float4*)vals)[idx];
      int b0, p;
      b0 = r.x >> 7; p = atomicAdd(&lcnt[b0], 1);
      CV[lofs[b0] + p] = make_int2(((r.x & 127) << 19) | c.x, __float_as_int(v.x));
      b0 = r.y >> 7; p = atomicAdd(&lcnt[b0], 1);
      CV[lofs[b0] + p] = make_int2(((r.y & 127) << 19) | c.y, __float_as_int(v.y));
      b0 = r.z >> 7; p = atomicAdd(&lcnt[b0], 1);
      CV[lofs[b0] + p] = make_int2(((r.z & 127) << 19) | c.z, __float_as_int(v.z));
      b0 = r.w >> 7; p = atomicAdd(&lcnt[b0], 1);
      CV[lofs[b0] + p] = make_int2(((r.w & 127) << 19) | c.w, __float_as_int(v.w));
    }
  }
}

// ===========================================================================
// in-LDS counting sort of each bucket (128 bins) -> exact CSR, in place.
// Also writes per-row offsets off[]. Integer LDS atomics only.
// ===========================================================================
__global__ __launch_bounds__(256) void local_sort_kernel(
    const int* __restrict__ gbase_, const int* __restrict__ gcnt_,
    int2* __restrict__ CV, int* __restrict__ off) {
  __shared__ int2 sorted[CAP];                 // 48 KB
  __shared__ int  binincl[RPB];
  __shared__ int  bincur[RPB];
  const int b   = blockIdx.x;
  const int s   = gbase_[b];
  const int cnt = gcnt_[b];
  const int tid = threadIdx.x;

  if (tid < RPB) bincur[tid] = 0;
  __syncthreads();
  // pass 1: histogram of row-local ids
  for (int i = tid; i < cnt; i += 256)
    atomicAdd(&bincur[CV[s + i].x >> 19], 1);
  __syncthreads();
  if (tid < RPB) binincl[tid] = bincur[tid];
  __syncthreads();
  // inclusive Hillis-Steele scan over 128 bins
  for (int ofs = 1; ofs < RPB; ofs <<= 1) {
    int v = (tid < RPB && tid >= ofs) ? binincl[tid - ofs] : 0;
    __syncthreads();
    if (tid < RPB) binincl[tid] += v;
    __syncthreads();
  }
  // exclusive starts; emit per-row CSR offsets; reset cursors
  if (tid < RPB) {
    int excl = binincl[tid] - bincur[tid];
    int r = b * RPB + tid;
    if (r < N_NODES) off[r] = s + excl;
    bincur[tid] = excl;
  }
  __syncthreads();

  if (cnt <= CAP) {
    // pass 2: scatter into LDS (int LDS atomic cursor), strip rowlocal bits
    for (int i = tid; i < cnt; i += 256) {
      int2 ed = CV[s + i];
      int p = atomicAdd(&bincur[ed.x >> 19], 1);
      sorted[p] = make_int2(ed.x & 0x7FFFF, ed.y);
    }
    __syncthreads();
    // pass 3: coalesced in-place write-back
    for (int i = tid; i < cnt; i += 256) CV[s + i] = sorted[i];
  } else {
    // unreachable for this dataset (cnt ~ Poisson(4096); CAP = mean + 32 sigma)
    for (int i = tid; i < cnt; i += 256) {
      int2 ed = CV[s + i];
      int p = atomicAdd(&bincur[ed.x >> 19], 1);
      CV[s + p] = make_int2(ed.x & 0x7FFFF, ed.y);
    }
  }
}

// ===========================================================================
// CSR SpMM, wave per row, register accumulate, no atomics.
// MODE==0: dst = A*x
// MODE==1: dst = (x0 + dst + x + A*x) * 0.25   (fused final mean; dst in-place)
// ===========================================================================
template <int MODE>
__global__ __launch_bounds__(256) void spmm_csr_kernel(
    const int*  __restrict__ off, const int2* __restrict__ CV,
    const float* __restrict__ x, float* __restrict__ dst,
    const float* __restrict__ x0) {
  const int lane = threadIdx.x & 63;
  int wid = blockIdx.x * (blockDim.x >> 6) + (threadIdx.x >> 6);
  const int nw = gridDim.x * (blockDim.x >> 6);
  for (int r = wid; r < N_NODES; r += nw) {
    int s = __builtin_amdgcn_readfirstlane(off[r]);
    int e = __builtin_amdgcn_readfirstlane(off[r + 1]);
    float acc = 0.f;
    int i = s;
    for (; i + 4 <= e; i += 4) {
      int2 a = CV[i], b = CV[i + 1], c = CV[i + 2], d = CV[i + 3];
      acc += __int_as_float(a.y) * x[a.x * EMB + lane];
      acc += __int_as_float(b.y) * x[b.x * EMB + lane];
      acc += __int_as_float(c.y) * x[c.x * EMB + lane];
      acc += __int_as_float(d.y) * x[d.x * EMB + lane];
    }
    for (; i < e; ++i) {
      int2 a = CV[i];
      acc += __int_as_float(a.y) * x[a.x * EMB + lane];
    }
    int o = r * EMB + lane;
    if (MODE) dst[o] = (x0[o] + dst[o] + x[o] + acc) * 0.25f;
    else      dst[o] = acc;
  }
}

// ===========================================================================
// Fallback (round-1 atomic path) if ws_size is too small
// ===========================================================================
__global__ __launch_bounds__(256) void init_kernel_fb(
    const float* __restrict__ user_emb, const float* __restrict__ item_emb,
    float* __restrict__ X, float* __restrict__ Y, float* __restrict__ out) {
  const long total4 = (long)N_NODES * EMB / 4;
  long g = (long)blockIdx.x * blockDim.x + threadIdx.x;
  if (g >= total4) return;
  const long user4 = (long)USER_NUM * EMB / 4;
  float4 v;
  if (g < user4) v = ((const float4*)user_emb)[g];
  else           v = ((const float4*)item_emb)[g - user4];
  ((float4*)X)[g]   = v;
  ((float4*)out)[g] = v;
  ((float4*)Y)[g]   = make_float4(0.f, 0.f, 0.f, 0.f);
}

__global__ __launch_bounds__(256) void spmm_atomic_kernel_fb(
    const float* __restrict__ vals, const int* __restrict__ rows,
    const int* __restrict__ cols, const float* __restrict__ x,
    float* __restrict__ y) {
  const int lane = threadIdx.x & 63;
  int wave = blockIdx.x * (blockDim.x >> 6) + (threadIdx.x >> 6);
  wave = __builtin_amdgcn_readfirstlane(wave);
  const int nwaves = gridDim.x * (blockDim.x >> 6);
  constexpr int U = 4;
  for (long base = (long)wave * U; base < NNZ; base += (long)nwaves * U) {
    int r[U], c[U]; float v[U];
#pragma unroll
    for (int u = 0; u < U; ++u) { r[u] = rows[base+u]; c[u] = cols[base+u]; v[u] = vals[base+u]; }
#pragma unroll
    for (int u = 0; u < U; ++u) {
      float xv = x[(long)c[u] * EMB + lane];
      unsafeAtomicAdd(&y[(long)r[u] * EMB + lane], v[u] * xv);
    }
  }
}

__global__ __launch_bounds__(256) void add_zero_kernel_fb(
    float* __restrict__ out, const float* __restrict__ S, float* __restrict__ Z) {
  const long total4 = (long)N_NODES * EMB / 4;
  long g = (long)blockIdx.x * blockDim.x + threadIdx.x;
  if (g >= total4) return;
  float4 a = ((float4*)out)[g];
  float4 s = ((const float4*)S)[g];
  a.x += s.x; a.y += s.y; a.z += s.z; a.w += s.w;
  ((float4*)out)[g] = a;
  ((float4*)Z)[g]   = make_float4(0.f, 0.f, 0.f, 0.f);
}

__global__ __launch_bounds__(256) void final_kernel_fb(
    float* __restrict__ out, const float* __restrict__ S) {
  const long total4 = (long)N_NODES * EMB / 4;
  long g = (long)blockIdx.x * blockDim.x + threadIdx.x;
  if (g >= total4) return;
  float4 a = ((float4*)out)[g];
  float4 s = ((const float4*)S)[g];
  a.x = (a.x + s.x) * 0.25f; a.y = (a.y + s.y) * 0.25f;
  a.z = (a.z + s.z) * 0.25f; a.w = (a.w + s.w) * 0.25f;
  ((float4*)out)[g] = a;
}

// ===========================================================================
extern "C" void kernel_launch(void* const* d_in, const int* in_sizes, int n_in,
                              void* d_out, int out_size, void* d_ws, size_t ws_size,
                              hipStream_t stream) {
  const float* user_emb = (const float*)d_in[0];
  const float* item_emb = (const float*)d_in[1];
  const float* adj_vals = (const float*)d_in[2];
  const int*   adj_rows = (const int*)d_in[3];
  const int*   adj_cols = (const int*)d_in[4];
  float* out = (float*)d_out;

  const size_t nodeF = (size_t)N_NODES * EMB;
  const long total4 = (long)N_NODES * EMB / 4;
  const int ew_blocks = (int)((total4 + 255) / 256);

  // ws layout: X | Y | CV | off | gcnt | gbase | gcur
  float* X     = (float*)d_ws;
  float* Y     = X + nodeF;
  int2*  CV    = (int2*)(Y + nodeF);
  int*   off   = (int*)(CV + NNZ);
  int*   gcnt  = off + (N_NODES + 1);
  int*   gbase = gcnt + NBUCK;
  int*   gcur  = gbase + NBUCK;
  const size_t need = 2 * nodeF * sizeof(float) + (size_t)NNZ * 8 +
                      (size_t)(N_NODES + 1 + 3 * NBUCK) * sizeof(int);

  if (ws_size >= need) {
    init_nodes_kernel<<<ew_blocks, 256, 0, stream>>>(user_emb, item_emb, X);
    zero_buckets_kernel<<<(NBUCK + 255) / 256, 256, 0, stream>>>(gcnt);
    hist_bucket_kernel<<<NEBLK, 256, 0, stream>>>(adj_rows, gcnt);
    scan_buckets_kernel<<<1, 256, 0, stream>>>(gcnt, gbase, gcur, off);
    scatter_bucket_kernel<<<NEBLK, 256, 0, stream>>>(adj_rows, adj_cols, adj_vals, gcur, CV);
    local_sort_kernel<<<NBUCK, 256, 0, stream>>>(gbase, gcnt, CV, off);
    const int spmm_blocks = 2048;
    // Y1 = A*X0 -> out ; Y2 = A*Y1 -> Y ; out = (X0 + Y1 + Y2 + A*Y2)/4
    spmm_csr_kernel<0><<<spmm_blocks, 256, 0, stream>>>(off, CV, X,   out, nullptr);
    spmm_csr_kernel<0><<<spmm_blocks, 256, 0, stream>>>(off, CV, out, Y,   nullptr);
    spmm_csr_kernel<1><<<spmm_blocks, 256, 0, stream>>>(off, CV, Y,   out, X);
  } else {
    // fallback: atomic path
    float* Xf = (float*)d_ws;
    float* Yf = Xf + nodeF;
    const int spmm_blocks = 2048;
    init_kernel_fb<<<ew_blocks, 256, 0, stream>>>(user_emb, item_emb, Xf, Yf, out);
    spmm_atomic_kernel_fb<<<spmm_blocks, 256, 0, stream>>>(adj_vals, adj_rows, adj_cols, Xf, Yf);
    add_zero_kernel_fb<<<ew_blocks, 256, 0, stream>>>(out, Yf, Xf);
    spmm_atomic_kernel_fb<<<spmm_blocks, 256, 0, stream>>>(adj_vals, adj_rows, adj_cols, Yf, Xf);
    add_zero_kernel_fb<<<ew_blocks, 256, 0, stream>>>(out, Xf, Yf);
    spmm_atomic_kernel_fb<<<spmm_blocks, 256, 0, stream>>>(adj_vals, adj_rows, adj_cols, Xf, Yf);
    final_kernel_fb<<<ew_blocks, 256, 0, stream>>>(out, Yf);
  }
}

// Round 9
// 1202.092 us; speedup vs baseline: 8.6819x; 1.2883x over previous
//
#include <hip/hip_runtime.h>

#define USER_NUM 200000
#define ITEM_NUM 100000
#define N_NODES  (USER_NUM + ITEM_NUM)
#define EMB      64
#define NNZ      9600000

#define RPB      128                                // rows per bucket
#define NBUCK    ((N_NODES + RPB - 1) / RPB)        // 2344
#define CHUNK_I4 4096                               // int4s per chunk = 16384 edges
#define NEBLK    ((NNZ / 4 + CHUNK_I4 - 1) / CHUNK_I4)  // 586
#define CAP      6144                               // LDS sort capacity (mean 4096 + 32 sigma)

// bf16 helpers (RNE pack, cheap unpack)
__device__ __forceinline__ ushort f2bf(float f) {
  uint u = __float_as_uint(f);
  u += 0x7FFFu + ((u >> 16) & 1u);
  return (ushort)(u >> 16);
}
__device__ __forceinline__ float bf_lo(uint w) { return __uint_as_float(w << 16); }
__device__ __forceinline__ float bf_hi(uint w) { return __uint_as_float(w & 0xFFFF0000u); }

// ===========================================================================
// init: Xh = bf16(concat(user_emb, item_emb))
// ===========================================================================
__global__ __launch_bounds__(256) void init_bf16_kernel(
    const float* __restrict__ user_emb,
    const float* __restrict__ item_emb,
    ushort* __restrict__ Xh) {
  const long total4 = (long)N_NODES * EMB / 4;
  long g = (long)blockIdx.x * blockDim.x + threadIdx.x;
  if (g >= total4) return;
  const long user4 = (long)USER_NUM * EMB / 4;
  float4 v;
  if (g < user4) v = ((const float4*)user_emb)[g];
  else           v = ((const float4*)item_emb)[g - user4];
  ushort4 h;
  h.x = f2bf(v.x); h.y = f2bf(v.y); h.z = f2bf(v.z); h.w = f2bf(v.w);
  ((ushort4*)Xh)[g] = h;
}

__global__ __launch_bounds__(256) void zero_buckets_kernel(int* __restrict__ gcnt) {
  int i = blockIdx.x * 256 + threadIdx.x;
  if (i < NBUCK) gcnt[i] = 0;
}

// ===========================================================================
// bucket histogram: LDS (integer) hist per chunk, merged once per bucket
// ===========================================================================
__global__ __launch_bounds__(256) void hist_bucket_kernel(
    const int* __restrict__ rows, int* __restrict__ gcnt) {
  __shared__ int lcnt[NBUCK];
  for (int i = threadIdx.x; i < NBUCK; i += 256) lcnt[i] = 0;
  __syncthreads();
  const int n4 = NNZ / 4;
  const int base = blockIdx.x * CHUNK_I4;
  for (int i = threadIdx.x; i < CHUNK_I4; i += 256) {
    int idx = base + i;
    if (idx < n4) {
      int4 r = ((const int4*)rows)[idx];
      atomicAdd(&lcnt[r.x >> 7], 1);
      atomicAdd(&lcnt[r.y >> 7], 1);
      atomicAdd(&lcnt[r.z >> 7], 1);
      atomicAdd(&lcnt[r.w >> 7], 1);
    }
  }
  __syncthreads();
  for (int b = threadIdx.x; b < NBUCK; b += 256) {
    int c = lcnt[b];
    if (c) atomicAdd(&gcnt[b], c);
  }
}

// ===========================================================================
// exclusive scan of bucket counts (single block); gcur=gbase; off[N]=NNZ
// ===========================================================================
__global__ __launch_bounds__(256) void scan_buckets_kernel(
    const int* __restrict__ gcnt, int* __restrict__ gbase,
    int* __restrict__ gcur, int* __restrict__ off) {
  __shared__ int sh[256];
  __shared__ int carry_sh;
  int tid = threadIdx.x;
  if (tid == 0) { carry_sh = 0; off[N_NODES] = NNZ; }
  __syncthreads();
  for (int base = 0; base < NBUCK; base += 256) {
    int idx = base + tid;
    int v = (idx < NBUCK) ? gcnt[idx] : 0;
    sh[tid] = v; __syncthreads();
#pragma unroll
    for (int ofs = 1; ofs < 256; ofs <<= 1) {
      int t = (tid >= ofs) ? sh[tid - ofs] : 0;
      __syncthreads();
      sh[tid] += t;
      __syncthreads();
    }
    int excl = carry_sh + sh[tid] - v;
    if (idx < NBUCK) { gbase[idx] = excl; gcur[idx] = excl; }
    int tot = sh[255];
    __syncthreads();
    if (tid == 0) carry_sh += tot;
    __syncthreads();
  }
}

// ===========================================================================
// bucket scatter: per-chunk LDS hist -> per-(chunk,bucket) reservation ->
// packed contiguous runs.  meta = (rowlocal<<19) | col
// ===========================================================================
__global__ __launch_bounds__(256) void scatter_bucket_kernel(
    const int* __restrict__ rows, const int* __restrict__ cols,
    const float* __restrict__ vals, int* __restrict__ gcur,
    int2* __restrict__ CV) {
  __shared__ int lcnt[NBUCK];
  __shared__ int lofs[NBUCK];
  for (int i = threadIdx.x; i < NBUCK; i += 256) lcnt[i] = 0;
  __syncthreads();
  const int n4 = NNZ / 4;
  const int base = blockIdx.x * CHUNK_I4;
  for (int i = threadIdx.x; i < CHUNK_I4; i += 256) {
    int idx = base + i;
    if (idx < n4) {
      int4 r = ((const int4*)rows)[idx];
      atomicAdd(&lcnt[r.x >> 7], 1);
      atomicAdd(&lcnt[r.y >> 7], 1);
      atomicAdd(&lcnt[r.z >> 7], 1);
      atomicAdd(&lcnt[r.w >> 7], 1);
    }
  }
  __syncthreads();
  for (int b = threadIdx.x; b < NBUCK; b += 256) {
    int c = lcnt[b];
    lofs[b] = c ? atomicAdd(&gcur[b], c) : 0;
    lcnt[b] = 0;
  }
  __syncthreads();
  for (int i = threadIdx.x; i < CHUNK_I4; i += 256) {
    int idx = base + i;
    if (idx < n4) {
      int4   r = ((const int4*)rows)[idx];
      int4   c = ((const int4*)cols)[idx];
      float4 v = ((const float4*)vals)[idx];
      int b0, p;
      b0 = r.x >> 7; p = atomicAdd(&lcnt[b0], 1);
      CV[lofs[b0] + p] = make_int2(((r.x & 127) << 19) | c.x, __float_as_int(v.x));
      b0 = r.y >> 7; p = atomicAdd(&lcnt[b0], 1);
      CV[lofs[b0] + p] = make_int2(((r.y & 127) << 19) | c.y, __float_as_int(v.y));
      b0 = r.z >> 7; p = atomicAdd(&lcnt[b0], 1);
      CV[lofs[b0] + p] = make_int2(((r.z & 127) << 19) | c.z, __float_as_int(v.z));
      b0 = r.w >> 7; p = atomicAdd(&lcnt[b0], 1);
      CV[lofs[b0] + p] = make_int2(((r.w & 127) << 19) | c.w, __float_as_int(v.w));
    }
  }
}

// ===========================================================================
// in-LDS counting sort of each bucket (128 bins) -> exact CSR, in place.
// ===========================================================================
__global__ __launch_bounds__(256) void local_sort_kernel(
    const int* __restrict__ gbase_, const int* __restrict__ gcnt_,
    int2* __restrict__ CV, int* __restrict__ off) {
  __shared__ int2 sorted[CAP];                 // 48 KB
  __shared__ int  binincl[RPB];
  __shared__ int  bincur[RPB];
  const int b   = blockIdx.x;
  const int s   = gbase_[b];
  const int cnt = gcnt_[b];
  const int tid = threadIdx.x;

  if (tid < RPB) bincur[tid] = 0;
  __syncthreads();
  for (int i = tid; i < cnt; i += 256)
    atomicAdd(&bincur[CV[s + i].x >> 19], 1);
  __syncthreads();
  if (tid < RPB) binincl[tid] = bincur[tid];
  __syncthreads();
  for (int ofs = 1; ofs < RPB; ofs <<= 1) {
    int v = (tid < RPB && tid >= ofs) ? binincl[tid - ofs] : 0;
    __syncthreads();
    if (tid < RPB) binincl[tid] += v;
    __syncthreads();
  }
  if (tid < RPB) {
    int excl = binincl[tid] - bincur[tid];
    int r = b * RPB + tid;
    if (r < N_NODES) off[r] = s + excl;
    bincur[tid] = excl;
  }
  __syncthreads();

  if (cnt <= CAP) {
    for (int i = tid; i < cnt; i += 256) {
      int2 ed = CV[s + i];
      int p = atomicAdd(&bincur[ed.x >> 19], 1);
      sorted[p] = make_int2(ed.x & 0x7FFFF, ed.y);
    }
    __syncthreads();
    for (int i = tid; i < cnt; i += 256) CV[s + i] = sorted[i];
  } else {
    for (int i = tid; i < cnt; i += 256) {
      int2 ed = CV[s + i];
      int p = atomicAdd(&bincur[ed.x >> 19], 1);
      CV[s + p] = make_int2(ed.x & 0x7FFFF, ed.y);
    }
  }
}

// ===========================================================================
// CSR SpMM, wave per row, bf16 gathers (fp32 accumulate), 2 edges / VMEM instr:
// lanes 0-31 = edge A, lanes 32-63 = edge B; each lane covers dims (2hl,2hl+1).
// MODE==0: dstf = A*x (f32), dsth = bf16(A*x)
// MODE==1: dstf = (x0 + y1 + y2 + A*x) * 0.25, x0 read from pristine inputs
// ===========================================================================
template <int MODE>
__global__ __launch_bounds__(256) void spmm_bf16_kernel(
    const int*  __restrict__ off, const int2* __restrict__ CV,
    const ushort* __restrict__ xh, float* __restrict__ dstf,
    ushort* __restrict__ dsth,
    const float* __restrict__ user_emb, const float* __restrict__ item_emb,
    const float* __restrict__ y1f, const float* __restrict__ y2f) {
  const uint* __restrict__ xu = (const uint*)xh;   // row = 32 uints (64 bf16)
  const int lane = threadIdx.x & 63;
  const int half = lane >> 5;                      // which edge of the pair
  const int hl   = lane & 31;                      // dim pair index
  int wid = blockIdx.x * (blockDim.x >> 6) + (threadIdx.x >> 6);
  const int nw = gridDim.x * (blockDim.x >> 6);
  for (int r = wid; r < N_NODES; r += nw) {
    int s = __builtin_amdgcn_readfirstlane(off[r]);
    int e = __builtin_amdgcn_readfirstlane(off[r + 1]);
    float ax = 0.f, ay = 0.f;
    int i = s;
    for (; i + 8 <= e; i += 8) {                   // 4 pairs = 8 edges
      int2 e0 = CV[i     + half];
      int2 e1 = CV[i + 2 + half];
      int2 e2 = CV[i + 4 + half];
      int2 e3 = CV[i + 6 + half];
      uint w0 = xu[e0.x * 32 + hl];
      uint w1 = xu[e1.x * 32 + hl];
      uint w2 = xu[e2.x * 32 + hl];
      uint w3 = xu[e3.x * 32 + hl];
      float v0 = __int_as_float(e0.y), v1 = __int_as_float(e1.y);
      float v2 = __int_as_float(e2.y), v3 = __int_as_float(e3.y);
      ax += v0 * bf_lo(w0); ay += v0 * bf_hi(w0);
      ax += v1 * bf_lo(w1); ay += v1 * bf_hi(w1);
      ax += v2 * bf_lo(w2); ay += v2 * bf_hi(w2);
      ax += v3 * bf_lo(w3); ay += v3 * bf_hi(w3);
    }
    for (; i < e; i += 2) {                        // tail, pair-steps
      int idx = i + half;
      int2 ed = CV[idx < e ? idx : (e - 1)];
      float v = (idx < e) ? __int_as_float(ed.y) : 0.f;
      uint w = xu[ed.x * 32 + hl];
      ax += v * bf_lo(w); ay += v * bf_hi(w);
    }
    ax += __shfl_xor(ax, 32, 64);                  // combine the two halves
    ay += __shfl_xor(ay, 32, 64);
    if (MODE == 0) {
      if (half == 0) {                             // f32 result, 256B/row
        float2 o; o.x = ax; o.y = ay;
        *(float2*)(dstf + r * EMB + 2 * hl) = o;
      } else {                                     // bf16 copy for next layer
        uint packed = (uint)f2bf(ax) | ((uint)f2bf(ay) << 16);
        ((uint*)dsth)[r * 32 + hl] = packed;
      }
    } else {
      if (half == 0) {
        int o = r * EMB + 2 * hl;
        float2 x0 = (r < USER_NUM)
            ? *(const float2*)(user_emb + (size_t)r * EMB + 2 * hl)
            : *(const float2*)(item_emb + (size_t)(r - USER_NUM) * EMB + 2 * hl);
        float2 a = *(const float2*)(y1f + o);
        float2 b = *(const float2*)(y2f + o);
        float2 res;
        res.x = (x0.x + a.x + b.x + ax) * 0.25f;
        res.y = (x0.y + a.y + b.y + ay) * 0.25f;
        *(float2*)(dstf + o) = res;
      }
    }
  }
}

// ===========================================================================
// Fallback (atomic path) if ws_size is too small
// ===========================================================================
__global__ __launch_bounds__(256) void init_kernel_fb(
    const float* __restrict__ user_emb, const float* __restrict__ item_emb,
    float* __restrict__ X, float* __restrict__ Y, float* __restrict__ out) {
  const long total4 = (long)N_NODES * EMB / 4;
  long g = (long)blockIdx.x * blockDim.x + threadIdx.x;
  if (g >= total4) return;
  const long user4 = (long)USER_NUM * EMB / 4;
  float4 v;
  if (g < user4) v = ((const float4*)user_emb)[g];
  else           v = ((const float4*)item_emb)[g - user4];
  ((float4*)X)[g]   = v;
  ((float4*)out)[g] = v;
  ((float4*)Y)[g]   = make_float4(0.f, 0.f, 0.f, 0.f);
}

__global__ __launch_bounds__(256) void spmm_atomic_kernel_fb(
    const float* __restrict__ vals, const int* __restrict__ rows,
    const int* __restrict__ cols, const float* __restrict__ x,
    float* __restrict__ y) {
  const int lane = threadIdx.x & 63;
  int wave = blockIdx.x * (blockDim.x >> 6) + (threadIdx.x >> 6);
  wave = __builtin_amdgcn_readfirstlane(wave);
  const int nwaves = gridDim.x * (blockDim.x >> 6);
  constexpr int U = 4;
  for (long base = (long)wave * U; base < NNZ; base += (long)nwaves * U) {
    int r[U], c[U]; float v[U];
#pragma unroll
    for (int u = 0; u < U; ++u) { r[u] = rows[base+u]; c[u] = cols[base+u]; v[u] = vals[base+u]; }
#pragma unroll
    for (int u = 0; u < U; ++u) {
      float xv = x[(long)c[u] * EMB + lane];
      unsafeAtomicAdd(&y[(long)r[u] * EMB + lane], v[u] * xv);
    }
  }
}

__global__ __launch_bounds__(256) void add_zero_kernel_fb(
    float* __restrict__ out, const float* __restrict__ S, float* __restrict__ Z) {
  const long total4 = (long)N_NODES * EMB / 4;
  long g = (long)blockIdx.x * blockDim.x + threadIdx.x;
  if (g >= total4) return;
  float4 a = ((float4*)out)[g];
  float4 s = ((const float4*)S)[g];
  a.x += s.x; a.y += s.y; a.z += s.z; a.w += s.w;
  ((float4*)out)[g] = a;
  ((float4*)Z)[g]   = make_float4(0.f, 0.f, 0.f, 0.f);
}

__global__ __launch_bounds__(256) void final_kernel_fb(
    float* __restrict__ out, const float* __restrict__ S) {
  const long total4 = (long)N_NODES * EMB / 4;
  long g = (long)blockIdx.x * blockDim.x + threadIdx.x;
  if (g >= total4) return;
  float4 a = ((float4*)out)[g];
  float4 s = ((const float4*)S)[g];
  a.x = (a.x + s.x) * 0.25f; a.y = (a.y + s.y) * 0.25f;
  a.z = (a.z + s.z) * 0.25f; a.w = (a.w + s.w) * 0.25f;
  ((float4*)out)[g] = a;
}

// ===========================================================================
extern "C" void kernel_launch(void* const* d_in, const int* in_sizes, int n_in,
                              void* d_out, int out_size, void* d_ws, size_t ws_size,
                              hipStream_t stream) {
  const float* user_emb = (const float*)d_in[0];
  const float* item_emb = (const float*)d_in[1];
  const float* adj_vals = (const float*)d_in[2];
  const int*   adj_rows = (const int*)d_in[3];
  const int*   adj_cols = (const int*)d_in[4];
  float* out = (float*)d_out;

  const size_t nodeF = (size_t)N_NODES * EMB;
  const long total4 = (long)N_NODES * EMB / 4;
  const int ew_blocks = (int)((total4 + 255) / 256);

  // ws layout: Y(f32) | CV | Xh(bf16) | H1(bf16) | off | gcnt | gbase | gcur
  float*  Y     = (float*)d_ws;
  int2*   CV    = (int2*)(Y + nodeF);
  ushort* Xh    = (ushort*)(CV + NNZ);
  ushort* H1    = Xh + nodeF;
  int*    off   = (int*)(H1 + nodeF);
  int*    gcnt  = off + (N_NODES + 1);
  int*    gbase = gcnt + NBUCK;
  int*    gcur  = gbase + NBUCK;
  const size_t need = nodeF * 4 + (size_t)NNZ * 8 + 2 * nodeF * 2 +
                      (size_t)(N_NODES + 1 + 3 * NBUCK) * sizeof(int);

  if (ws_size >= need) {
    init_bf16_kernel<<<ew_blocks, 256, 0, stream>>>(user_emb, item_emb, Xh);
    zero_buckets_kernel<<<(NBUCK + 255) / 256, 256, 0, stream>>>(gcnt);
    hist_bucket_kernel<<<NEBLK, 256, 0, stream>>>(adj_rows, gcnt);
    scan_buckets_kernel<<<1, 256, 0, stream>>>(gcnt, gbase, gcur, off);
    scatter_bucket_kernel<<<NEBLK, 256, 0, stream>>>(adj_rows, adj_cols, adj_vals, gcur, CV);
    local_sort_kernel<<<NBUCK, 256, 0, stream>>>(gbase, gcnt, CV, off);
    const int spmm_blocks = 2048;
    // y1 = A*x0:    f32 -> out, bf16 -> H1
    spmm_bf16_kernel<0><<<spmm_blocks, 256, 0, stream>>>(
        off, CV, Xh, out, H1, nullptr, nullptr, nullptr, nullptr);
    // y2 = A*y1:    f32 -> Y,   bf16 -> Xh (x0h dead after spmm1)
    spmm_bf16_kernel<0><<<spmm_blocks, 256, 0, stream>>>(
        off, CV, H1, Y, Xh, nullptr, nullptr, nullptr, nullptr);
    // out = (x0 + y1 + y2 + A*y2) / 4
    spmm_bf16_kernel<1><<<spmm_blocks, 256, 0, stream>>>(
        off, CV, Xh, out, nullptr, user_emb, item_emb, out, Y);
  } else {
    // fallback: atomic path
    float* Xf = (float*)d_ws;
    float* Yf = Xf + nodeF;
    const int spmm_blocks = 2048;
    init_kernel_fb<<<ew_blocks, 256, 0, stream>>>(user_emb, item_emb, Xf, Yf, out);
    spmm_atomic_kernel_fb<<<spmm_blocks, 256, 0, stream>>>(adj_vals, adj_rows, adj_cols, Xf, Yf);
    add_zero_kernel_fb<<<ew_blocks, 256, 0, stream>>>(out, Yf, Xf);
    spmm_atomic_kernel_fb<<<spmm_blocks, 256, 0, stream>>>(adj_vals, adj_rows, adj_cols, Yf, Xf);
    add_zero_kernel_fb<<<ew_blocks, 256, 0, stream>>>(out, Xf, Yf);
    spmm_atomic_kernel_fb<<<spmm_blocks, 256, 0, stream>>>(adj_vals, adj_rows, adj_cols, Xf, Yf);
    final_kernel_fb<<<ew_blocks, 256, 0, stream>>>(out, Yf);
  }
}